// Round 8
// baseline (181.288 us; speedup 1.0000x reference)
//
#include <hip/hip_runtime.h>
#include <cmath>

#define N_ 32
#define B_ 64
#define T_ 8192
#define SLICES 8                    // 1024-t slices per b
#define PSTRIDE 2176                // 1024 pp + 1024 pn + 4*32 stats

typedef float floatx4 __attribute__((ext_vector_type(4)));

// ---------------- Stage 1: 2-KB-run reads -> fp8 LDS -> wave-quadrant MFMA ------------
// grid 512 = 64 b * 8 slices; block 512 (8 waves); 64 KB LDS -> 2 blocks/CU.
// Pearson is invariant to the reference's per-n affine normalization -> raw data.
// DRAM-page-friendly: each row is read as a 2-KB contiguous run per chunk (8 threads/row,
// 128-B per-instruction segments over 16 back-to-back instructions). No scattered global
// writes. fp8 Gram via MFMA (numerics validated in round 7, absmax 0.0); stats exact fp32
// from the pre-conversion registers.
__global__ __launch_bounds__(512, 4) void k_fused(const float* __restrict__ pos,
                                                  const float* __restrict__ neg,
                                                  float* __restrict__ partial) {
    __shared__ __align__(16) unsigned char smem[2][64 * 512];   // 65536 B

    const int bid = blockIdx.x;
    const int b = bid >> 3, c = bid & 7;
    const int tid = threadIdx.x;
    const int wave = tid >> 6, lane = tid & 63;

    // load/stats role: row R (0..31 pos n, 32..63 neg n), 8 threads per row
    const int R = tid >> 3, sub = tid & 7;
    const int tz = R >> 5, n = R & 31;
    const float4* s4 = (const float4*)((tz ? neg : pos) + ((long)(n * B_ + b)) * T_ + c * 1024);
    const int rsw = R & 15;                     // row swizzle key (same as tensor-local row&15)

    // MFMA role: quadrant (qi,qj) of Gram `mat`; A side = pos rows, B side = mat's rows
    const int mat = wave >> 2, qi = (wave >> 1) & 1, qj = wave & 1;
    const int m16 = lane & 15, h2 = lane >> 4;
    const int arow = qi * 16 + m16, brow = qj * 16 + m16;
    const int aR = arow, bR = mat * 32 + brow;
    const int aswz = arow & 15, bswz = brow & 15;

    floatx4 acc = {};
    float ssum = 0.f, ssq = 0.f;
    float4 v[16];

#define LOADCH(ch)                                                   \
    _Pragma("unroll") for (int i = 0; i < 16; ++i)                   \
        v[i] = s4[(ch) * 128 + sub + 8 * i];

#define PROCESS(buf)                                                 \
    _Pragma("unroll") for (int i = 0; i < 16; ++i) {                 \
        float4 x = v[i];                                             \
        ssum += x.x + x.y + x.z + x.w;                               \
        ssq = fmaf(x.x, x.x, ssq); ssq = fmaf(x.y, x.y, ssq);        \
        ssq = fmaf(x.z, x.z, ssq); ssq = fmaf(x.w, x.w, ssq);        \
        int pk = __builtin_amdgcn_cvt_pk_fp8_f32(x.x, x.y, 0, false);\
        pk = __builtin_amdgcn_cvt_pk_fp8_f32(x.z, x.w, pk, true);    \
        int f = sub + 8 * i;                                         \
        int u = f >> 1, hf = f & 1;                                  \
        int uph = (u & 48) | ((u ^ rsw) & 15);                       \
        *(int*)&smem[buf][R * 512 + uph * 8 + hf * 4] = pk;          \
    }

#define MFMACH(buf)                                                  \
    _Pragma("unroll") for (int kk = 0; kk < 16; ++kk) {              \
        int u = kk * 4 + h2;                                         \
        int ua = (u & 48) | ((u ^ aswz) & 15);                       \
        int ub = (u & 48) | ((u ^ bswz) & 15);                       \
        long long av = *(const long long*)&smem[buf][aR * 512 + ua * 8]; \
        long long bv = *(const long long*)&smem[buf][bR * 512 + ub * 8]; \
        acc = __builtin_amdgcn_mfma_f32_16x16x32_fp8_fp8(av, bv, acc, 0, 0, 0); \
    }

    LOADCH(0);
    PROCESS(0);                                   // waits chunk0 loads; stages buf0
    LOADCH(1);                                    // chunk1 loads in flight across barrier
    asm volatile("s_waitcnt lgkmcnt(0)" ::: "memory");
    asm volatile("s_barrier" ::: "memory");       // buf0 visible (vmcnt untouched)
    MFMACH(0);
    PROCESS(1);                                   // waits chunk1 loads; stages buf1
    asm volatile("s_waitcnt lgkmcnt(0)" ::: "memory");
    asm volatile("s_barrier" ::: "memory");       // buf1 visible
    MFMACH(1);

#undef LOADCH
#undef PROCESS
#undef MFMACH

    // per-row stats: the 8 threads sharing a row are adjacent lanes -> butterfly
    ssum += __shfl_xor(ssum, 1); ssum += __shfl_xor(ssum, 2); ssum += __shfl_xor(ssum, 4);
    ssq += __shfl_xor(ssq, 1); ssq += __shfl_xor(ssq, 2); ssq += __shfl_xor(ssq, 4);

    float* out = partial + (long)bid * PSTRIDE;
    if (sub == 0) {
        out[2048 + tz * 64 + n] = ssum;           // sx  / sy
        out[2048 + tz * 64 + 32 + n] = ssq;       // sx2 / sy2
    }

    // C/D layout 16x16 (m89-verified, dtype-independent): col = lane&15, row = h2*4+reg
#pragma unroll
    for (int reg = 0; reg < 4; ++reg) {
        int rr = qi * 16 + h2 * 4 + reg;
        int cc = qj * 16 + m16;
        out[mat * 1024 + rr * 32 + cc] = acc[reg];
    }
}

// ---------------- Stage 2: reduce 8 slice partials -> per-b stats ----------------
__global__ void k_reduce(const float* __restrict__ partial, float* __restrict__ red) {
    const int b = blockIdx.y;
    const int o = blockIdx.x * 128 + threadIdx.x;   // 0..2175
    const float* in = partial + (long)b * SLICES * PSTRIDE;
    float s = 0.f;
#pragma unroll
    for (int c = 0; c < SLICES; ++c) s += in[c * PSTRIDE + o];
    red[(long)b * PSTRIDE + o] = s;
}

// ---------------- Stage 3: per-entry pearson over b, exp terms ----------------
__global__ void k_entries(const float* __restrict__ red, double* __restrict__ blocksums) {
    const int tid = threadIdx.x;
    const int w = tid >> 6, lane = tid & 63;
    const int entry = blockIdx.x * 4 + w;
    const int mat = entry >> 10;       // 0 = pp, 1 = pn
    const int idx = entry & 1023;
    const int n = idx >> 5, m = idx & 31;

    const float* rb = red + (long)lane * PSTRIDE;
    float g = rb[mat * 1024 + idx];
    float sxn = rb[2048 + n];
    float sx2n = rb[2080 + n];
    float sym, sy2m;
    if (mat == 0) {
        sym = rb[2048 + m];
        sy2m = rb[2080 + m];
    } else {
        sym = rb[2112 + m];
        sy2m = rb[2144 + m];
    }

    double num = (double)T_ * (double)g - (double)sxn * (double)sym;
    double vx = (double)T_ * (double)sx2n - (double)sxn * (double)sxn;
    double vy = (double)T_ * (double)sy2m - (double)sym * (double)sym;
    double contrib = 1.0 - num / sqrt(vx * vy);

#pragma unroll
    for (int off = 32; off; off >>= 1) contrib += __shfl_down(contrib, off);

    __shared__ double s_pos[4], s_neg[4];
    if (lane == 0) {
        double d = contrib * (1.0 / B_);
        double term = exp(d / 0.08);
        double p = 0.0, q = 0.0;
        if (mat == 0) {
            if (n < m) p = term;     // strict upper triangle only
        } else {
            q = term;
        }
        s_pos[w] = p;
        s_neg[w] = q;
    }
    __syncthreads();
    if (tid == 0) {
        blocksums[blockIdx.x * 2 + 0] = s_pos[0] + s_pos[1] + s_pos[2] + s_pos[3];
        blocksums[blockIdx.x * 2 + 1] = s_neg[0] + s_neg[1] + s_neg[2] + s_neg[3];
    }
}

// ---------------- Stage 4: final scalar ----------------
__global__ void k_final(const double* __restrict__ blocksums, float* __restrict__ out) {
    __shared__ double sp[256], sn[256];
    const int tid = threadIdx.x;
    double p = 0.0, q = 0.0;
    for (int i = tid; i < 512; i += 256) {
        p += blocksums[2 * i + 0];
        q += blocksums[2 * i + 1];
    }
    sp[tid] = p;
    sn[tid] = q;
    __syncthreads();
    for (int s = 128; s; s >>= 1) {
        if (tid < s) {
            sp[tid] += sp[tid + s];
            sn[tid] += sn[tid + s];
        }
        __syncthreads();
    }
    if (tid == 0) out[0] = (float)log10(sp[0] / sn[0] + 1.0);
}

extern "C" void kernel_launch(void* const* d_in, const int* in_sizes, int n_in,
                              void* d_out, int out_size, void* d_ws, size_t ws_size,
                              hipStream_t stream) {
    const float* pos = (const float*)d_in[0];
    const float* neg = (const float*)d_in[1];
    float* out = (float*)d_out;

    char* ws = (char*)d_ws;
    float* partial = (float*)ws;                               // 512*2176*4 = 4,456,448 B
    float* red = (float*)(ws + (size_t)512 * PSTRIDE * 4);     //  64*2176*4 =   557,056 B
    double* blocksums = (double*)(ws + (size_t)512 * PSTRIDE * 4 + (size_t)64 * PSTRIDE * 4);

    k_fused<<<512, 512, 0, stream>>>(pos, neg, partial);
    k_reduce<<<dim3(17, 64), 128, 0, stream>>>(partial, red);
    k_entries<<<512, 256, 0, stream>>>(red, blocksums);
    k_final<<<1, 256, 0, stream>>>(blocksums, out);
}